// Round 14
// baseline (33396.878 us; speedup 1.0000x reference)
//
#include <hip/hip_runtime.h>
#include <hip/hip_bf16.h>

typedef __bf16 bf16x8 __attribute__((ext_vector_type(8)));
typedef float f32x4 __attribute__((ext_vector_type(4)));

#define TT 256
#define BB 64
#define VOC 512
#define EMBD 256
#define NNH 1536
#define KA 1792   // EMBD + NNH
#define KB 3072   // NNH + NNH
#define G4I 6144  // 4*NNH

// hi/lo frag buffer (rnf history): 48 kc x 4 m x (hi 512 | lo 512)
#define FRSZ 196608
// hi-only frag state (h0/h1/emb): 48 kc x 4 m x 512
#define FRSZH 98304
// emb hi-only frag per t: 8 kc x 4 m x 512
#define EFSZH 16384

__device__ __forceinline__ float sigm_(float x){
  x = fminf(fmaxf(x, -30.f), 30.f);
  return 1.f / (1.f + __expf(-x));
}
__device__ __forceinline__ float tanh_(float x){
  x = fminf(fmaxf(x, -15.f), 15.f);
  float e = __expf(2.f * x);
  return (e - 1.f) / (e + 1.f);
}

// ---- transpose + hi/lo split: src (R,C) f32 -> dst (C,R) bf16 hi/lo (for ewT/owT)
__global__ __launch_bounds__(256) void tsplit(const float* __restrict__ src, int R, int C,
                                              __bf16* __restrict__ dhi, __bf16* __restrict__ dlo){
  __shared__ float tile[32][33];
  int c0 = blockIdx.x * 32, r0 = blockIdx.y * 32;
  int tx = threadIdx.x & 31, ty = threadIdx.x >> 5;
  #pragma unroll
  for (int i = 0; i < 4; i++){
    int r = ty + i * 8;
    tile[r][tx] = src[(size_t)(r0 + r) * C + (c0 + tx)];
  }
  __syncthreads();
  #pragma unroll
  for (int i = 0; i < 4; i++){
    int cl = ty + i * 8;
    float v = tile[tx][cl];
    __bf16 h = (__bf16)v;
    size_t o = (size_t)(c0 + cl) * R + (r0 + tx);
    dhi[o] = h;
    dlo[o] = (__bf16)(v - (float)h);
  }
}

// ---- elementwise hi/lo split (x input)
__global__ __launch_bounds__(256) void vsplit(const float* __restrict__ src, int n,
                                              __bf16* __restrict__ dhi, __bf16* __restrict__ dlo){
  int i = blockIdx.x * 256 + threadIdx.x;
  if (i < n){
    float v = src[i];
    __bf16 h = (__bf16)v;
    dhi[i] = h;
    dlo[i] = (__bf16)(v - (float)h);
  }
}

// ---- h-state (64,1536) f32 -> HI-ONLY frag order
__global__ __launch_bounds__(256) void vsplit_fragH(const float* __restrict__ src,
                                                    __bf16* __restrict__ dst){
  int i = blockIdx.x * 256 + threadIdx.x;   // 0..98303
  int b = i / NNH, n = i % NNH;
  int kc = n >> 5, lgA = (n >> 3) & 3, j = n & 7;
  size_t idx = (size_t)(kc * 4 + (b >> 4)) * 512 + (size_t)(lgA * 16 + (b & 15)) * 8 + j;
  dst[idx] = (__bf16)src[i];
}

// ---- weights (K,6144) f32 -> HI-ONLY frag stream [b(96)][kc(nkc)][g(4)][512 bf16]
__global__ __launch_bounds__(256) void wfrag(const float* __restrict__ w, int nkc,
                                             __bf16* __restrict__ dst){
  int cid = blockIdx.x * 4 + (threadIdx.x >> 6);
  int lane = threadIdx.x & 63;
  int g = cid & 3;
  int bk = cid >> 2;
  int kc = bk % nkc;
  int b = bk / nkc;
  int l15 = lane & 15, lg = lane >> 4;
  int col = g * NNH + b * 16 + l15;
  int k0 = kc * 32 + lg * 8;
  bf16x8 hv;
  #pragma unroll
  for (int j = 0; j < 8; j++)
    hv[j] = (__bf16)w[(size_t)(k0 + j) * G4I + col];
  *(bf16x8*)(dst + (size_t)cid * 512 + lane * 8) = hv;
}

// ---- embedding GEMM (3-pass, exact inputs): x @ emb_w -> emb HI-ONLY frag per t
__global__ __launch_bounds__(256) void gemm_emb(const __bf16* __restrict__ Ah, const __bf16* __restrict__ Al,
    const __bf16* __restrict__ BTh, const __bf16* __restrict__ BTl, __bf16* __restrict__ embf){
  int lane = threadIdx.x & 63, wv = threadIdx.x >> 6;
  int l15 = lane & 15, lg = lane >> 4;
  int col = blockIdx.y * 64 + wv * 16 + l15;
  const __bf16* bh_p = BTh + (size_t)col * VOC + lg * 8;
  const __bf16* bl_p = BTl + (size_t)col * VOC + lg * 8;
  size_t abase = (size_t)(blockIdx.x * 64 + l15) * VOC + lg * 8;
  const __bf16* ah_p = Ah + abase;
  const __bf16* al_p = Al + abase;
  f32x4 acc[4];
  #pragma unroll
  for (int m = 0; m < 4; m++){ acc[m][0]=0.f; acc[m][1]=0.f; acc[m][2]=0.f; acc[m][3]=0.f; }
  for (int kc = 0; kc < 16; ++kc){
    bf16x8 bh = *(const bf16x8*)(bh_p + kc * 32);
    bf16x8 bl = *(const bf16x8*)(bl_p + kc * 32);
    bf16x8 ah[4], al[4];
    #pragma unroll
    for (int m = 0; m < 4; m++){
      ah[m] = *(const bf16x8*)(ah_p + (size_t)(m * 16) * VOC + kc * 32);
      al[m] = *(const bf16x8*)(al_p + (size_t)(m * 16) * VOC + kc * 32);
    }
    #pragma unroll
    for (int m = 0; m < 4; m++) acc[m] = __builtin_amdgcn_mfma_f32_16x16x32_bf16(ah[m], bh, acc[m], 0, 0, 0);
    #pragma unroll
    for (int m = 0; m < 4; m++) acc[m] = __builtin_amdgcn_mfma_f32_16x16x32_bf16(al[m], bh, acc[m], 0, 0, 0);
    #pragma unroll
    for (int m = 0; m < 4; m++) acc[m] = __builtin_amdgcn_mfma_f32_16x16x32_bf16(ah[m], bl, acc[m], 0, 0, 0);
  }
  // hi-only frag epilogue: t = blockIdx.x, k-dim = col
  __bf16* bt = embf + (size_t)blockIdx.x * EFSZH;
  int kc = col >> 5, lgA = (col >> 3) & 3, jA = col & 7;
  #pragma unroll
  for (int m = 0; m < 4; m++){
    #pragma unroll
    for (int v = 0; v < 4; v++){
      int l15A = lg * 4 + v;
      size_t oi = (size_t)(kc * 4 + m) * 512 + (size_t)(lgA * 16 + l15A) * 8 + jA;
      bt[oi] = (__bf16)acc[m][v];
    }
  }
}

// ---- output GEMM (3-pass, exact): rn hi/lo frag history @ out_w + bias -> logits f32
__global__ __launch_bounds__(256) void gemm_out(const __bf16* __restrict__ rnf,
    const __bf16* __restrict__ BTh, const __bf16* __restrict__ BTl,
    const float* __restrict__ bias, float* __restrict__ out){
  int lane = threadIdx.x & 63, wv = threadIdx.x >> 6;
  int l15 = lane & 15, lg = lane >> 4;
  int t = blockIdx.x;
  const __bf16* ab = rnf + (size_t)(t + 1) * FRSZ;
  int col = blockIdx.y * 64 + wv * 16 + l15;
  const __bf16* bh_p = BTh + (size_t)col * NNH + lg * 8;
  const __bf16* bl_p = BTl + (size_t)col * NNH + lg * 8;
  int lane8 = lane * 8;
  f32x4 acc[4];
  #pragma unroll
  for (int m = 0; m < 4; m++){ acc[m][0]=0.f; acc[m][1]=0.f; acc[m][2]=0.f; acc[m][3]=0.f; }
  for (int kc = 0; kc < 48; ++kc){
    bf16x8 bh = *(const bf16x8*)(bh_p + kc * 32);
    bf16x8 bl = *(const bf16x8*)(bl_p + kc * 32);
    bf16x8 ah[4], al[4];
    #pragma unroll
    for (int m = 0; m < 4; m++){
      const __bf16* ap = ab + (size_t)(kc * 4 + m) * 1024 + lane8;
      ah[m] = *(const bf16x8*)ap;
      al[m] = *(const bf16x8*)(ap + 512);
    }
    #pragma unroll
    for (int m = 0; m < 4; m++) acc[m] = __builtin_amdgcn_mfma_f32_16x16x32_bf16(ah[m], bh, acc[m], 0, 0, 0);
    #pragma unroll
    for (int m = 0; m < 4; m++) acc[m] = __builtin_amdgcn_mfma_f32_16x16x32_bf16(al[m], bh, acc[m], 0, 0, 0);
    #pragma unroll
    for (int m = 0; m < 4; m++) acc[m] = __builtin_amdgcn_mfma_f32_16x16x32_bf16(ah[m], bl, acc[m], 0, 0, 0);
  }
  #pragma unroll
  for (int m = 0; m < 4; m++){
    int row = t * 64 + m * 16 + lg * 4;
    #pragma unroll
    for (int v = 0; v < 4; v++)
      out[(size_t)(row + v) * VOC + col] = acc[m][v] + bias[col];
  }
}

// ==== single-pass gate-bundled K-split region: A hi, B hi ====
// per kc: 4 A-frags + 4 B-frags, 16 MFMAs. A-ring depth 3, B-ring depth 4 (period 12).
#define AKG(S, KC) { _Pragma("unroll") \
    for (int m = 0; m < 4; m++) \
      Ah##S[m] = *(const bf16x8*)(ap + (size_t)(KC) * 2048 + m * 512 + lane8); }
#define BKG(S, KC) { _Pragma("unroll") \
    for (int g = 0; g < 4; g++) \
      Bh##S[g] = *(const bf16x8*)(bp + (size_t)(KC) * 2048 + g * 512 + lane8); }
#define MM2(SA, SB) { \
    _Pragma("unroll") for (int m = 0; m < 4; m++) _Pragma("unroll") for (int g = 0; g < 4; g++) \
      acc[m * 4 + g] = __builtin_amdgcn_mfma_f32_16x16x32_bf16(Ah##SA[m], Bh##SB[g], acc[m * 4 + g], 0, 0, 0); }

// body i: consume A-set i%3 / B-set i%4, then reload them for kc i+3 / i+4
#define BODY(I, SA, SB) \
  if ((I) < nkc){ \
    MM2(SA, SB) \
    if ((I) + 3 < nkc) AKG(SA, (I) + 3) \
    if ((I) + 4 < nkc) BKG(SB, (I) + 4) \
  }

// nkc in {3,4,6}; prologue may read B up to kc 3 (harmless in-workspace overrun,
// buffers are padded by their successors). Fully unrolled, wave-uniform guards.
__device__ __forceinline__ void regionKG(f32x4 (&acc)[16], const __bf16* __restrict__ ap,
                                         const __bf16* __restrict__ bp, int nkc, int lane8)
{
  bf16x8 Ah0[4], Ah1[4], Ah2[4];
  bf16x8 Bh0[4], Bh1[4], Bh2[4], Bh3[4];
  AKG(0, 0)
  if (nkc > 1) AKG(1, 1)
  if (nkc > 2) AKG(2, 2)
  BKG(0, 0) BKG(1, 1) BKG(2, 2) BKG(3, 3)
  BODY(0, 0, 0)
  BODY(1, 1, 1)
  BODY(2, 2, 2)
  BODY(3, 0, 3)
  BODY(4, 1, 0)
  BODY(5, 2, 1)
}

// ---- fused K-split LSTM step (384 blocks):
//   blocks 0..191  : layer1 step k-1; tile = bid>>1, K-half = bid&1 (half0=h0, half1=h1)
//   blocks 192..383: layer0 step k;   tile, K-half likewise (28 kc each)
// Each half-block: MFMA region + intra-block reduce -> partial preactivations ->
// global slot + agent-scope counter; SECOND finisher merges and runs the cell.
__global__ __launch_bounds__(512, 2) void lstm_step(int k,
  const __bf16* __restrict__ w0f, const __bf16* __restrict__ w1f,
  const float* __restrict__ b0, const float* __restrict__ b1,
  const __bf16* __restrict__ embt,
  const __bf16* __restrict__ h0r, __bf16* __restrict__ h0w,
  const __bf16* __restrict__ h1r, __bf16* __restrict__ h1w,
  __bf16* __restrict__ rnh,
  float* __restrict__ c0, float* __restrict__ c1,
  float* __restrict__ pslot, int* __restrict__ pcnt)
{
  const bool isB = blockIdx.x < 192;
  if (isB && k == 0) return;
  if (!isB && k == TT) return;
  const int bid2 = isB ? blockIdx.x : (blockIdx.x - 192);
  const int blk = bid2 >> 1, half = bid2 & 1;
  const int n0 = blk * 16;
  const int ctile = isB ? blk : (96 + blk);
  const int lane = threadIdx.x & 63, wv = threadIdx.x >> 6;
  const int l15 = lane & 15, lg = lane >> 4;
  const int lane8 = lane * 8;

  f32x4 acc[16];
  #pragma unroll
  for (int i = 0; i < 16; i++){ acc[i][0]=0.f; acc[i][1]=0.f; acc[i][2]=0.f; acc[i][3]=0.f; }

  if (isB){
    // layer1: 96 kc split at the h0/h1 boundary; 48 kc per half, 6 kc/wave
    const int start = wv * 6;
    const __bf16* ap = (half ? h1r : h0r) + (size_t)start * 2048;
    const __bf16* bp = w1f + ((size_t)blk * 96 + half * 48 + start) * 2048;
    regionKG(acc, ap, bp, 6, lane8);
  } else {
    // layer0: 56 kc = [emb 8 | h0 48]; half0 = emb8 + h0[0..19], half1 = h0[20..47]
    const __bf16* ap; int nkc, boff;
    if (half == 0){
      if (wv < 2){ ap = embt + (size_t)(wv * 4) * 2048; nkc = 4; boff = wv * 4; }
      else {
        int w = wv - 2;
        int start = (w < 2) ? w * 4 : 8 + (w - 2) * 3;   // 0,4,8,11,14,17
        nkc = (w < 2) ? 4 : 3;
        ap = h0r + (size_t)start * 2048; boff = 8 + start;
      }
    } else {
      int start = (wv < 4) ? wv * 4 : 16 + (wv - 4) * 3; // 0,4,8,12,16,19,22,25
      nkc = (wv < 4) ? 4 : 3;
      ap = h0r + (size_t)(20 + start) * 2048; boff = 28 + start;
    }
    const __bf16* bp = w0f + ((size_t)blk * 56 + boff) * 2048;
    regionKG(acc, ap, bp, nkc, lane8);
  }

  // two-stage intra-block K-partial reduction: 8 -> 4 in LDS
  __shared__ float lin[4][64][68];
  __shared__ int amSecond;
  if (wv >= 4){
    #pragma unroll
    for (int m = 0; m < 4; m++)
      #pragma unroll
      for (int g = 0; g < 4; g++)
        *(f32x4*)&lin[wv - 4][g * 16 + l15][m * 16 + lg * 4] = acc[m * 4 + g];
  }
  __syncthreads();
  if (wv < 4){
    #pragma unroll
    for (int m = 0; m < 4; m++)
      #pragma unroll
      for (int g = 0; g < 4; g++){
        f32x4 part = *(const f32x4*)&lin[wv][g * 16 + l15][m * 16 + lg * 4];
        acc[m * 4 + g][0] += part[0]; acc[m * 4 + g][1] += part[1];
        acc[m * 4 + g][2] += part[2]; acc[m * 4 + g][3] += part[3];
        *(f32x4*)&lin[wv][g * 16 + l15][m * 16 + lg * 4] = acc[m * 4 + g];
      }
  }
  __syncthreads();

  // per-thread partial preactivations for this K-half
  const int j = threadIdx.x & 15, rr = threadIdx.x >> 4;   // j: n_rel, rr: batch row 0..31
  float ps[2][4];
  #pragma unroll
  for (int half2 = 0; half2 < 2; half2++){
    int r = rr + half2 * 32;
    #pragma unroll
    for (int g = 0; g < 4; g++){
      float s = 0.f;
      #pragma unroll
      for (int w = 0; w < 4; w++) s += lin[w][g * 16 + j][r];
      ps[half2][g] = s;
    }
  }

  // publish partial, then count; SECOND finisher merges + runs the cell
  float* myslot = pslot + ((size_t)ctile * 2 + half) * 4096;
  #pragma unroll
  for (int half2 = 0; half2 < 2; half2++){
    int r = rr + half2 * 32;
    #pragma unroll
    for (int g = 0; g < 4; g++) myslot[r * 64 + g * 16 + j] = ps[half2][g];
  }
  __threadfence();
  __syncthreads();
  if (threadIdx.x == 0)
    amSecond = (__hip_atomic_fetch_add(&pcnt[ctile], 1, __ATOMIC_ACQ_REL,
                                       __HIP_MEMORY_SCOPE_AGENT) == 1);
  __syncthreads();
  if (!amSecond) return;
  __builtin_amdgcn_fence(__ATOMIC_ACQUIRE, "agent");

  const float* os = pslot + ((size_t)ctile * 2 + (half ^ 1)) * 4096;
  const float* bias = isB ? b1 : b0;
  float* cst = isB ? c1 : c0;
  __bf16* of = isB ? h1w : h0w;
  #pragma unroll
  for (int half2 = 0; half2 < 2; half2++){
    int r = rr + half2 * 32;
    float s0 = ps[half2][0] + os[r * 64 + j];
    float s1 = ps[half2][1] + os[r * 64 + 16 + j];
    float s2 = ps[half2][2] + os[r * 64 + 32 + j];
    float s3 = ps[half2][3] + os[r * 64 + 48 + j];
    int n = n0 + j;
    float fv = sigm_(s0 + bias[n]);
    float iv = sigm_(s1 + bias[NNH + n]);
    float ov = sigm_(s2 + bias[2 * NNH + n]);
    float gv = tanh_(s3 + bias[3 * NNH + n]);
    int ci = r * NNH + n;
    float cn = fv * cst[ci] + iv * gv;
    cst[ci] = cn;
    float hn = ov * tanh_(cn);
    __bf16 hb = (__bf16)hn;
    int kcp = n >> 5, lgA = (n >> 3) & 3, j8 = n & 7, mb = r >> 4, l15b = r & 15;
    size_t oh = (size_t)(kcp * 4 + mb) * 512 + (size_t)(lgA * 16 + l15b) * 8 + j8;
    of[oh] = hb;
    if (isB){
      __bf16 lb = (__bf16)(hn - (float)hb);
      size_t oi = (size_t)(kcp * 4 + mb) * 1024 + (size_t)(lgA * 16 + l15b) * 8 + j8;
      __builtin_nontemporal_store(hb, &rnh[oi]);
      __builtin_nontemporal_store(lb, &rnh[oi + 512]);
    }
  }
  if (threadIdx.x == 0)
    __hip_atomic_store(&pcnt[ctile], 0, __ATOMIC_RELAXED, __HIP_MEMORY_SCOPE_AGENT);
}

extern "C" void kernel_launch(void* const* d_in, const int* in_sizes, int n_in,
                              void* d_out, int out_size, void* d_ws, size_t ws_size,
                              hipStream_t stream)
{
  (void)in_sizes; (void)n_in; (void)out_size;
  const float* x_in = (const float*)d_in[0];
  const float* emw  = (const float*)d_in[1];
  const float* w0   = (const float*)d_in[2];
  const float* b0   = (const float*)d_in[3];
  const float* w1   = (const float*)d_in[4];
  const float* b1   = (const float*)d_in[5];
  const float* outw = (const float*)d_in[6];
  const float* outb = (const float*)d_in[7];
  const float* h0i  = (const float*)d_in[8];
  const float* c0i  = (const float*)d_in[9];
  const float* h1i  = (const float*)d_in[10];
  const float* c1i  = (const float*)d_in[11];
  float* logits = (float*)d_out;

  char* p = (char*)d_ws;
  auto ab = [&](size_t bytes)->char*{ char* r = p; p += (bytes + 255) & ~(size_t)255; return r; };
  __bf16* w0f  = (__bf16*)ab((size_t)96 * 56 * 4 * 1024);   // 22.0 MB hi-only stream
  __bf16* w1f  = (__bf16*)ab((size_t)96 * 96 * 4 * 1024);   // 37.7 MB
  __bf16* ewTh = (__bf16*)ab((size_t)EMBD * VOC * 2);
  __bf16* ewTl = (__bf16*)ab((size_t)EMBD * VOC * 2);
  __bf16* owTh = (__bf16*)ab((size_t)VOC * NNH * 2);
  __bf16* owTl = (__bf16*)ab((size_t)VOC * NNH * 2);
  __bf16* xh   = (__bf16*)ab((size_t)TT * BB * VOC * 2);
  __bf16* xl   = (__bf16*)ab((size_t)TT * BB * VOC * 2);
  __bf16* embf = (__bf16*)ab((size_t)TT * EFSZH * 2);       // 8.4 MB hi-only frag
  __bf16* rnf  = (__bf16*)ab((size_t)(TT + 1) * FRSZ * 2);  // 101 MB hi/lo history (NT)
  __bf16* h0f  = (__bf16*)ab((size_t)2 * FRSZH * 2);        // h0 hi-only ping-pong (hot)
  __bf16* h1f  = (__bf16*)ab((size_t)2 * FRSZH * 2);        // h1 hi-only ping-pong (hot)
  float* c0 = (float*)ab((size_t)BB * NNH * 4);
  float* c1 = (float*)ab((size_t)BB * NNH * 4);
  float* pslot = (float*)ab((size_t)192 * 2 * 4096 * 4);    // 6.3 MB partial slots
  int* pcnt = (int*)ab((size_t)192 * 4);
  if ((size_t)(p - (char*)d_ws) > ws_size) return;  // ws too small: fail visibly

  const int H = BB * NNH;

  // one-time-per-call prep
  hipMemsetAsync(pcnt, 0, 192 * 4, stream);
  wfrag<<<96 * 56 * 4 / 4, 256, 0, stream>>>(w0, 56, w0f);
  wfrag<<<96 * 96 * 4 / 4, 256, 0, stream>>>(w1, 96, w1f);
  tsplit<<<dim3(EMBD / 32, VOC / 32), 256, 0, stream>>>(emw, VOC, EMBD, ewTh, ewTl);
  tsplit<<<dim3(VOC / 32, NNH / 32), 256, 0, stream>>>(outw, NNH, VOC, owTh, owTl);
  {
    int nin = TT * BB * VOC;
    vsplit<<<nin / 256, 256, 0, stream>>>(x_in, nin, xh, xl);
  }
  vsplit_fragH<<<H / 256, 256, 0, stream>>>(h0i, h0f + FRSZH);  // h0 parity 1 (read at k=0)
  vsplit_fragH<<<H / 256, 256, 0, stream>>>(h1i, h1f);          // h1 parity 0 (read at k=1)
  hipMemcpyAsync(c0, c0i, (size_t)H * 4, hipMemcpyDeviceToDevice, stream);
  hipMemcpyAsync(c1, c1i, (size_t)H * 4, hipMemcpyDeviceToDevice, stream);

  // embedding -> hi-only frag emb buffer
  gemm_emb<<<dim3(TT * BB / 64, EMBD / 64), 256, 0, stream>>>(xh, xl, ewTh, ewTl, embf);

  // pipelined recurrence: kernel k = layer0 step k + layer1 step k-1 (both K-split 2-way)
  for (int k = 0; k <= TT; ++k){
    int tA = (k < TT) ? k : 0;
    lstm_step<<<384, 512, 0, stream>>>(k, w0f, w1f, b0, b1,
        embf + (size_t)tA * EFSZH,
        h0f + (size_t)((k + 1) & 1) * FRSZH, h0f + (size_t)(k & 1) * FRSZH,
        h1f + (size_t)((k + 1) & 1) * FRSZH, h1f + (size_t)(k & 1) * FRSZH,
        rnf + (size_t)k * FRSZ,
        c0, c1, pslot, pcnt);
  }

  // logits = rn hi/lo frag history @ out_w + out_b (exact 3-pass)
  gemm_out<<<dim3(TT, VOC / 64), 256, 0, stream>>>(rnf, owTh, owTl, outb, logits);
}

// Round 15
// 19273.787 us; speedup vs baseline: 1.7328x; 1.7328x over previous
//
#include <hip/hip_runtime.h>
#include <hip/hip_bf16.h>
#include <hip/hip_cooperative_groups.h>

namespace cg = cooperative_groups;

typedef __bf16 bf16x8 __attribute__((ext_vector_type(8)));
typedef float f32x4 __attribute__((ext_vector_type(4)));

#define TT 256
#define BB 64
#define VOC 512
#define EMBD 256
#define NNH 1536
#define KA 1792   // EMBD + NNH
#define KB 3072   // NNH + NNH
#define G4I 6144  // 4*NNH

// hi/lo frag buffer (rnf history): 48 kc x 4 m x (hi 512 | lo 512)
#define FRSZ 196608
// hi-only frag state (h0/h1/emb): 48 kc x 4 m x 512
#define FRSZH 98304
// emb hi-only frag per t: 8 kc x 4 m x 512
#define EFSZH 16384

__device__ __forceinline__ float sigm_(float x){
  x = fminf(fmaxf(x, -30.f), 30.f);
  return 1.f / (1.f + __expf(-x));
}
__device__ __forceinline__ float tanh_(float x){
  x = fminf(fmaxf(x, -15.f), 15.f);
  float e = __expf(2.f * x);
  return (e - 1.f) / (e + 1.f);
}

// ---- transpose + hi/lo split: src (R,C) f32 -> dst (C,R) bf16 hi/lo (for ewT/owT)
__global__ __launch_bounds__(256) void tsplit(const float* __restrict__ src, int R, int C,
                                              __bf16* __restrict__ dhi, __bf16* __restrict__ dlo){
  __shared__ float tile[32][33];
  int c0 = blockIdx.x * 32, r0 = blockIdx.y * 32;
  int tx = threadIdx.x & 31, ty = threadIdx.x >> 5;
  #pragma unroll
  for (int i = 0; i < 4; i++){
    int r = ty + i * 8;
    tile[r][tx] = src[(size_t)(r0 + r) * C + (c0 + tx)];
  }
  __syncthreads();
  #pragma unroll
  for (int i = 0; i < 4; i++){
    int cl = ty + i * 8;
    float v = tile[tx][cl];
    __bf16 h = (__bf16)v;
    size_t o = (size_t)(c0 + cl) * R + (r0 + tx);
    dhi[o] = h;
    dlo[o] = (__bf16)(v - (float)h);
  }
}

// ---- elementwise hi/lo split (x input)
__global__ __launch_bounds__(256) void vsplit(const float* __restrict__ src, int n,
                                              __bf16* __restrict__ dhi, __bf16* __restrict__ dlo){
  int i = blockIdx.x * 256 + threadIdx.x;
  if (i < n){
    float v = src[i];
    __bf16 h = (__bf16)v;
    dhi[i] = h;
    dlo[i] = (__bf16)(v - (float)h);
  }
}

// ---- h-state (64,1536) f32 -> HI-ONLY frag order
__global__ __launch_bounds__(256) void vsplit_fragH(const float* __restrict__ src,
                                                    __bf16* __restrict__ dst){
  int i = blockIdx.x * 256 + threadIdx.x;   // 0..98303
  int b = i / NNH, n = i % NNH;
  int kc = n >> 5, lgA = (n >> 3) & 3, j = n & 7;
  size_t idx = (size_t)(kc * 4 + (b >> 4)) * 512 + (size_t)(lgA * 16 + (b & 15)) * 8 + j;
  dst[idx] = (__bf16)src[i];
}

// ---- weights (K,6144) f32 -> HI-ONLY frag stream [b(96)][kc(nkc)][g(4)][512 bf16]
__global__ __launch_bounds__(256) void wfrag(const float* __restrict__ w, int nkc,
                                             __bf16* __restrict__ dst){
  int cid = blockIdx.x * 4 + (threadIdx.x >> 6);
  int lane = threadIdx.x & 63;
  int g = cid & 3;
  int bk = cid >> 2;
  int kc = bk % nkc;
  int b = bk / nkc;
  int l15 = lane & 15, lg = lane >> 4;
  int col = g * NNH + b * 16 + l15;
  int k0 = kc * 32 + lg * 8;
  bf16x8 hv;
  #pragma unroll
  for (int j = 0; j < 8; j++)
    hv[j] = (__bf16)w[(size_t)(k0 + j) * G4I + col];
  *(bf16x8*)(dst + (size_t)cid * 512 + lane * 8) = hv;
}

// ---- embedding GEMM (3-pass, exact inputs): x @ emb_w -> emb HI-ONLY frag per t
__global__ __launch_bounds__(256) void gemm_emb(const __bf16* __restrict__ Ah, const __bf16* __restrict__ Al,
    const __bf16* __restrict__ BTh, const __bf16* __restrict__ BTl, __bf16* __restrict__ embf){
  int lane = threadIdx.x & 63, wv = threadIdx.x >> 6;
  int l15 = lane & 15, lg = lane >> 4;
  int col = blockIdx.y * 64 + wv * 16 + l15;
  const __bf16* bh_p = BTh + (size_t)col * VOC + lg * 8;
  const __bf16* bl_p = BTl + (size_t)col * VOC + lg * 8;
  size_t abase = (size_t)(blockIdx.x * 64 + l15) * VOC + lg * 8;
  const __bf16* ah_p = Ah + abase;
  const __bf16* al_p = Al + abase;
  f32x4 acc[4];
  #pragma unroll
  for (int m = 0; m < 4; m++){ acc[m][0]=0.f; acc[m][1]=0.f; acc[m][2]=0.f; acc[m][3]=0.f; }
  for (int kc = 0; kc < 16; ++kc){
    bf16x8 bh = *(const bf16x8*)(bh_p + kc * 32);
    bf16x8 bl = *(const bf16x8*)(bl_p + kc * 32);
    bf16x8 ah[4], al[4];
    #pragma unroll
    for (int m = 0; m < 4; m++){
      ah[m] = *(const bf16x8*)(ah_p + (size_t)(m * 16) * VOC + kc * 32);
      al[m] = *(const bf16x8*)(al_p + (size_t)(m * 16) * VOC + kc * 32);
    }
    #pragma unroll
    for (int m = 0; m < 4; m++) acc[m] = __builtin_amdgcn_mfma_f32_16x16x32_bf16(ah[m], bh, acc[m], 0, 0, 0);
    #pragma unroll
    for (int m = 0; m < 4; m++) acc[m] = __builtin_amdgcn_mfma_f32_16x16x32_bf16(al[m], bh, acc[m], 0, 0, 0);
    #pragma unroll
    for (int m = 0; m < 4; m++) acc[m] = __builtin_amdgcn_mfma_f32_16x16x32_bf16(ah[m], bl, acc[m], 0, 0, 0);
  }
  // hi-only frag epilogue: t = blockIdx.x, k-dim = col
  __bf16* bt = embf + (size_t)blockIdx.x * EFSZH;
  int kc = col >> 5, lgA = (col >> 3) & 3, jA = col & 7;
  #pragma unroll
  for (int m = 0; m < 4; m++){
    #pragma unroll
    for (int v = 0; v < 4; v++){
      int l15A = lg * 4 + v;
      size_t oi = (size_t)(kc * 4 + m) * 512 + (size_t)(lgA * 16 + l15A) * 8 + jA;
      bt[oi] = (__bf16)acc[m][v];
    }
  }
}

// ---- output GEMM (3-pass, exact): rn hi/lo frag history @ out_w + bias -> logits f32
__global__ __launch_bounds__(256) void gemm_out(const __bf16* __restrict__ rnf,
    const __bf16* __restrict__ BTh, const __bf16* __restrict__ BTl,
    const float* __restrict__ bias, float* __restrict__ out){
  int lane = threadIdx.x & 63, wv = threadIdx.x >> 6;
  int l15 = lane & 15, lg = lane >> 4;
  int t = blockIdx.x;
  const __bf16* ab = rnf + (size_t)(t + 1) * FRSZ;
  int col = blockIdx.y * 64 + wv * 16 + l15;
  const __bf16* bh_p = BTh + (size_t)col * NNH + lg * 8;
  const __bf16* bl_p = BTl + (size_t)col * NNH + lg * 8;
  int lane8 = lane * 8;
  f32x4 acc[4];
  #pragma unroll
  for (int m = 0; m < 4; m++){ acc[m][0]=0.f; acc[m][1]=0.f; acc[m][2]=0.f; acc[m][3]=0.f; }
  for (int kc = 0; kc < 48; ++kc){
    bf16x8 bh = *(const bf16x8*)(bh_p + kc * 32);
    bf16x8 bl = *(const bf16x8*)(bl_p + kc * 32);
    bf16x8 ah[4], al[4];
    #pragma unroll
    for (int m = 0; m < 4; m++){
      const __bf16* ap = ab + (size_t)(kc * 4 + m) * 1024 + lane8;
      ah[m] = *(const bf16x8*)ap;
      al[m] = *(const bf16x8*)(ap + 512);
    }
    #pragma unroll
    for (int m = 0; m < 4; m++) acc[m] = __builtin_amdgcn_mfma_f32_16x16x32_bf16(ah[m], bh, acc[m], 0, 0, 0);
    #pragma unroll
    for (int m = 0; m < 4; m++) acc[m] = __builtin_amdgcn_mfma_f32_16x16x32_bf16(al[m], bh, acc[m], 0, 0, 0);
    #pragma unroll
    for (int m = 0; m < 4; m++) acc[m] = __builtin_amdgcn_mfma_f32_16x16x32_bf16(ah[m], bl, acc[m], 0, 0, 0);
  }
  #pragma unroll
  for (int m = 0; m < 4; m++){
    int row = t * 64 + m * 16 + lg * 4;
    #pragma unroll
    for (int v = 0; v < 4; v++)
      out[(size_t)(row + v) * VOC + col] = acc[m][v] + bias[col];
  }
}

// ==== single-pass gate-bundled K-split region: A hi, B hi ====
// per kc: 4 A-frags + 4 B-frags, 16 MFMAs. A-ring depth 3, B-ring depth 4 (period 12).
#define AKG(S, KC) { _Pragma("unroll") \
    for (int m = 0; m < 4; m++) \
      Ah##S[m] = *(const bf16x8*)(ap + (size_t)(KC) * 2048 + m * 512 + lane8); }
#define BKG(S, KC) { _Pragma("unroll") \
    for (int g = 0; g < 4; g++) \
      Bh##S[g] = *(const bf16x8*)(bp + (size_t)(KC) * 2048 + g * 512 + lane8); }
#define MM2(SA, SB) { \
    _Pragma("unroll") for (int m = 0; m < 4; m++) _Pragma("unroll") for (int g = 0; g < 4; g++) \
      acc[m * 4 + g] = __builtin_amdgcn_mfma_f32_16x16x32_bf16(Ah##SA[m], Bh##SB[g], acc[m * 4 + g], 0, 0, 0); }

// body i: consume A-set i%3 / B-set i%4, then reload them for kc i+3 / i+4
#define BODY(I, SA, SB) \
  if ((I) < nkc){ \
    MM2(SA, SB) \
    if ((I) + 3 < nkc) AKG(SA, (I) + 3) \
    if ((I) + 4 < nkc) BKG(SB, (I) + 4) \
  }

// nkc in {6,7,8,12}; fully unrolled 12 slots, wave-uniform guards
__device__ __forceinline__ void regionKG(f32x4 (&acc)[16], const __bf16* __restrict__ ap,
                                         const __bf16* __restrict__ bp, int nkc, int lane8)
{
  bf16x8 Ah0[4], Ah1[4], Ah2[4];
  bf16x8 Bh0[4], Bh1[4], Bh2[4], Bh3[4];
  AKG(0, 0) AKG(1, 1) AKG(2, 2)
  BKG(0, 0) BKG(1, 1) BKG(2, 2) BKG(3, 3)
  BODY(0, 0, 0)
  BODY(1, 1, 1)
  BODY(2, 2, 2)
  BODY(3, 0, 3)
  BODY(4, 1, 0)
  BODY(5, 2, 1)
  BODY(6, 0, 2)
  BODY(7, 1, 3)
  BODY(8, 2, 0)
  BODY(9, 0, 1)
  BODY(10, 1, 2)
  BODY(11, 2, 3)
}

// ---- persistent cooperative LSTM: one launch, k-loop, grid.sync() per step.
// Blocks 0..95 = layer0 (step k); 96..191 = layer1 (step k-1).
// r13 compute structure verbatim; c-state in registers; rnf history NT-streamed.
__global__ __launch_bounds__(512, 2) void lstm_persist(
  const __bf16* __restrict__ w0f, const __bf16* __restrict__ w1f,
  const float* __restrict__ b0, const float* __restrict__ b1,
  const __bf16* __restrict__ embf,
  __bf16* __restrict__ h0f, __bf16* __restrict__ h1f,
  __bf16* __restrict__ rnf,
  const float* __restrict__ c0i, const float* __restrict__ c1i)
{
  cg::grid_group grid = cg::this_grid();
  const bool isB = blockIdx.x >= 96;
  const int blk = isB ? (blockIdx.x - 96) : blockIdx.x;
  const int n0 = blk * 16;
  const int lane = threadIdx.x & 63, wv = threadIdx.x >> 6;
  const int l15 = lane & 15, lg = lane >> 4;
  const int lane8 = lane * 8;
  const float* bias = isB ? b1 : b0;

  // k-invariant per-wave weight pointer
  const int gstartA = (wv == 0) ? 0 : (8 + (wv - 1) * 7);
  const int nkcA = (wv == 0) ? 8 : ((wv == 7) ? 6 : 7);
  const __bf16* bp_w = isB ? (w1f + ((size_t)blk * 96 + wv * 12) * 2048)
                           : (w0f + ((size_t)blk * 56 + gstartA) * 2048);

  // persistent per-thread cell state: block owns c[:, n0:n0+16]
  const int j = threadIdx.x & 15, rr = (threadIdx.x >> 4) & 31;
  const float* cin = isB ? c1i : c0i;
  float creg0 = cin[(size_t)rr * NNH + n0 + j];
  float creg1 = cin[(size_t)(rr + 32) * NNH + n0 + j];

  __shared__ float lin[4][64][68];

  for (int k = 0; k <= TT; ++k){
    const bool active = isB ? (k >= 1) : (k < TT);
    if (active){
      f32x4 acc[16];
      #pragma unroll
      for (int i = 0; i < 16; i++){ acc[i][0]=0.f; acc[i][1]=0.f; acc[i][2]=0.f; acc[i][3]=0.f; }

      const __bf16* h0r = h0f + (size_t)((k + 1) & 1) * FRSZH;
      if (isB){
        const __bf16* h1r = h1f + (size_t)((k + 1) & 1) * FRSZH;   // h1(k-2)
        const __bf16* ap = (wv < 4) ? (h0r + (size_t)(wv * 12) * 2048)
                                    : (h1r + (size_t)((wv - 4) * 12) * 2048);
        regionKG(acc, ap, bp_w, 12, lane8);
      } else {
        const __bf16* embt = embf + (size_t)k * EFSZH;
        const __bf16* ap = (wv == 0) ? embt : (h0r + (size_t)(gstartA - 8) * 2048);
        regionKG(acc, ap, bp_w, nkcA, lane8);
      }

      // two-stage K-partial reduction: 8 -> 4 in LDS -> epilogue sums 4
      if (wv >= 4){
        #pragma unroll
        for (int m = 0; m < 4; m++)
          #pragma unroll
          for (int g = 0; g < 4; g++)
            *(f32x4*)&lin[wv - 4][g * 16 + l15][m * 16 + lg * 4] = acc[m * 4 + g];
      }
      __syncthreads();
      if (wv < 4){
        #pragma unroll
        for (int m = 0; m < 4; m++)
          #pragma unroll
          for (int g = 0; g < 4; g++){
            f32x4 part = *(const f32x4*)&lin[wv][g * 16 + l15][m * 16 + lg * 4];
            acc[m * 4 + g][0] += part[0]; acc[m * 4 + g][1] += part[1];
            acc[m * 4 + g][2] += part[2]; acc[m * 4 + g][3] += part[3];
            *(f32x4*)&lin[wv][g * 16 + l15][m * 16 + lg * 4] = acc[m * 4 + g];
          }
      }
      __syncthreads();

      __bf16* of = isB ? (h1f + (size_t)(k & 1) * FRSZH)   // h1(k-1)
                       : (h0f + (size_t)(k & 1) * FRSZH);  // h0(k)
      __bf16* rnh = rnf + (size_t)k * FRSZ;
      #pragma unroll
      for (int half = 0; half < 2; half++){
        int r = rr + half * 32;
        float s0 = 0.f, s1 = 0.f, s2 = 0.f, s3 = 0.f;
        #pragma unroll
        for (int w = 0; w < 4; w++){
          s0 += lin[w][j][r];
          s1 += lin[w][16 + j][r];
          s2 += lin[w][32 + j][r];
          s3 += lin[w][48 + j][r];
        }
        int n = n0 + j;
        float fv = sigm_(s0 + bias[n]);
        float iv = sigm_(s1 + bias[NNH + n]);
        float ov = sigm_(s2 + bias[2 * NNH + n]);
        float gv = tanh_(s3 + bias[3 * NNH + n]);
        float cold = half ? creg1 : creg0;
        float cn = fv * cold + iv * gv;
        if (half) creg1 = cn; else creg0 = cn;
        float hn = ov * tanh_(cn);
        __bf16 hb = (__bf16)hn;
        int kcp = n >> 5, lgA2 = (n >> 3) & 3, j8 = n & 7, mb = r >> 4, l15b = r & 15;
        size_t oh = (size_t)(kcp * 4 + mb) * 512 + (size_t)(lgA2 * 16 + l15b) * 8 + j8;
        of[oh] = hb;
        if (isB){
          __bf16 lb = (__bf16)(hn - (float)hb);
          size_t oi = (size_t)(kcp * 4 + mb) * 1024 + (size_t)(lgA2 * 16 + l15b) * 8 + j8;
          __builtin_nontemporal_store(hb, &rnh[oi]);
          __builtin_nontemporal_store(lb, &rnh[oi + 512]);
        }
      }
    }
    __threadfence();   // release h writes to device scope
    grid.sync();       // step barrier
  }
}

extern "C" void kernel_launch(void* const* d_in, const int* in_sizes, int n_in,
                              void* d_out, int out_size, void* d_ws, size_t ws_size,
                              hipStream_t stream)
{
  (void)in_sizes; (void)n_in; (void)out_size;
  const float* x_in = (const float*)d_in[0];
  const float* emw  = (const float*)d_in[1];
  const float* w0   = (const float*)d_in[2];
  const float* b0   = (const float*)d_in[3];
  const float* w1   = (const float*)d_in[4];
  const float* b1   = (const float*)d_in[5];
  const float* outw = (const float*)d_in[6];
  const float* outb = (const float*)d_in[7];
  const float* h0i  = (const float*)d_in[8];
  const float* c0i  = (const float*)d_in[9];
  const float* h1i  = (const float*)d_in[10];
  const float* c1i  = (const float*)d_in[11];
  float* logits = (float*)d_out;

  char* p = (char*)d_ws;
  auto ab = [&](size_t bytes)->char*{ char* r = p; p += (bytes + 255) & ~(size_t)255; return r; };
  __bf16* w0f  = (__bf16*)ab((size_t)96 * 56 * 4 * 1024);   // 22.0 MB hi-only stream
  __bf16* w1f  = (__bf16*)ab((size_t)96 * 96 * 4 * 1024);   // 37.7 MB
  __bf16* ewTh = (__bf16*)ab((size_t)EMBD * VOC * 2);
  __bf16* ewTl = (__bf16*)ab((size_t)EMBD * VOC * 2);
  __bf16* owTh = (__bf16*)ab((size_t)VOC * NNH * 2);
  __bf16* owTl = (__bf16*)ab((size_t)VOC * NNH * 2);
  __bf16* xh   = (__bf16*)ab((size_t)TT * BB * VOC * 2);
  __bf16* xl   = (__bf16*)ab((size_t)TT * BB * VOC * 2);
  __bf16* embf = (__bf16*)ab((size_t)TT * EFSZH * 2);       // 8.4 MB hi-only frag
  __bf16* rnf  = (__bf16*)ab((size_t)(TT + 1) * FRSZ * 2);  // 101 MB hi/lo history (NT)
  __bf16* h0f  = (__bf16*)ab((size_t)2 * FRSZH * 2);        // h0 hi-only ping-pong (hot)
  __bf16* h1f  = (__bf16*)ab((size_t)2 * FRSZH * 2);        // h1 hi-only ping-pong (hot)
  if ((size_t)(p - (char*)d_ws) > ws_size) return;  // ws too small: fail visibly

  const int H = BB * NNH;

  // one-time-per-call prep
  wfrag<<<96 * 56 * 4 / 4, 256, 0, stream>>>(w0, 56, w0f);
  wfrag<<<96 * 96 * 4 / 4, 256, 0, stream>>>(w1, 96, w1f);
  tsplit<<<dim3(EMBD / 32, VOC / 32), 256, 0, stream>>>(emw, VOC, EMBD, ewTh, ewTl);
  tsplit<<<dim3(VOC / 32, NNH / 32), 256, 0, stream>>>(outw, NNH, VOC, owTh, owTl);
  {
    int nin = TT * BB * VOC;
    vsplit<<<nin / 256, 256, 0, stream>>>(x_in, nin, xh, xl);
  }
  vsplit_fragH<<<H / 256, 256, 0, stream>>>(h0i, h0f + FRSZH);  // h0 parity 1 (read at k=0)
  vsplit_fragH<<<H / 256, 256, 0, stream>>>(h1i, h1f);          // h1 parity 0 (read at k=1)

  // embedding -> hi-only frag emb buffer
  gemm_emb<<<dim3(TT * BB / 64, EMBD / 64), 256, 0, stream>>>(xh, xl, ewTh, ewTl, embf);

  // persistent cooperative recurrence (replaces 257 step launches)
  {
    void* args[] = { (void*)&w0f, (void*)&w1f, (void*)&b0, (void*)&b1,
                     (void*)&embf, (void*)&h0f, (void*)&h1f, (void*)&rnf,
                     (void*)&c0i, (void*)&c1i };
    hipLaunchCooperativeKernel((void*)lstm_persist, dim3(192), dim3(512),
                               args, 0, stream);
  }

  // logits = rn hi/lo frag history @ out_w + out_b (exact 3-pass)
  gemm_out<<<dim3(TT, VOC / 64), 256, 0, stream>>>(rnf, owTh, owTl, outb, logits);
}

// Round 17
// 4449.327 us; speedup vs baseline: 7.5061x; 4.3318x over previous
//
#include <hip/hip_runtime.h>
#include <hip/hip_bf16.h>

typedef __bf16 bf16x8 __attribute__((ext_vector_type(8)));
typedef float f32x4 __attribute__((ext_vector_type(4)));

#define TT 256
#define BB 64
#define VOC 512
#define EMBD 256
#define NNH 1536
#define KA 1792   // EMBD + NNH
#define KB 3072   // NNH + NNH
#define G4I 6144  // 4*NNH

// hi/lo frag buffer (rnf history): 48 kc x 4 m x (hi 512 | lo 512)
#define FRSZ 196608
// hi-only frag state (h0/h1/emb): 48 kc x 4 m x 512
#define FRSZH 98304
// emb hi-only frag per t: 8 kc x 4 m x 512
#define EFSZH 16384

__device__ __forceinline__ float sigm_(float x){
  x = fminf(fmaxf(x, -30.f), 30.f);
  return 1.f / (1.f + __expf(-x));
}
__device__ __forceinline__ float tanh_(float x){
  x = fminf(fmaxf(x, -15.f), 15.f);
  float e = __expf(2.f * x);
  return (e - 1.f) / (e + 1.f);
}

// ---- transpose + hi/lo split: src (R,C) f32 -> dst (C,R) bf16 hi/lo (for ewT/owT)
__global__ __launch_bounds__(256) void tsplit(const float* __restrict__ src, int R, int C,
                                              __bf16* __restrict__ dhi, __bf16* __restrict__ dlo){
  __shared__ float tile[32][33];
  int c0 = blockIdx.x * 32, r0 = blockIdx.y * 32;
  int tx = threadIdx.x & 31, ty = threadIdx.x >> 5;
  #pragma unroll
  for (int i = 0; i < 4; i++){
    int r = ty + i * 8;
    tile[r][tx] = src[(size_t)(r0 + r) * C + (c0 + tx)];
  }
  __syncthreads();
  #pragma unroll
  for (int i = 0; i < 4; i++){
    int cl = ty + i * 8;
    float v = tile[tx][cl];
    __bf16 h = (__bf16)v;
    size_t o = (size_t)(c0 + cl) * R + (r0 + tx);
    dhi[o] = h;
    dlo[o] = (__bf16)(v - (float)h);
  }
}

// ---- elementwise hi/lo split (x input)
__global__ __launch_bounds__(256) void vsplit(const float* __restrict__ src, int n,
                                              __bf16* __restrict__ dhi, __bf16* __restrict__ dlo){
  int i = blockIdx.x * 256 + threadIdx.x;
  if (i < n){
    float v = src[i];
    __bf16 h = (__bf16)v;
    dhi[i] = h;
    dlo[i] = (__bf16)(v - (float)h);
  }
}

// ---- h-state (64,1536) f32 -> HI-ONLY frag order
__global__ __launch_bounds__(256) void vsplit_fragH(const float* __restrict__ src,
                                                    __bf16* __restrict__ dst){
  int i = blockIdx.x * 256 + threadIdx.x;   // 0..98303
  int b = i / NNH, n = i % NNH;
  int kc = n >> 5, lgA = (n >> 3) & 3, j = n & 7;
  size_t idx = (size_t)(kc * 4 + (b >> 4)) * 512 + (size_t)(lgA * 16 + (b & 15)) * 8 + j;
  dst[idx] = (__bf16)src[i];
}

// ---- weights (K,6144) f32 -> HI-ONLY frag stream [b(96)][kc(nkc)][g(4)][512 bf16]
__global__ __launch_bounds__(256) void wfrag(const float* __restrict__ w, int nkc,
                                             __bf16* __restrict__ dst){
  int cid = blockIdx.x * 4 + (threadIdx.x >> 6);
  int lane = threadIdx.x & 63;
  int g = cid & 3;
  int bk = cid >> 2;
  int kc = bk % nkc;
  int b = bk / nkc;
  int l15 = lane & 15, lg = lane >> 4;
  int col = g * NNH + b * 16 + l15;
  int k0 = kc * 32 + lg * 8;
  bf16x8 hv;
  #pragma unroll
  for (int j = 0; j < 8; j++)
    hv[j] = (__bf16)w[(size_t)(k0 + j) * G4I + col];
  *(bf16x8*)(dst + (size_t)cid * 512 + lane * 8) = hv;
}

// ---- embedding GEMM (3-pass, exact inputs): x @ emb_w -> emb HI-ONLY frag per t
__global__ __launch_bounds__(256) void gemm_emb(const __bf16* __restrict__ Ah, const __bf16* __restrict__ Al,
    const __bf16* __restrict__ BTh, const __bf16* __restrict__ BTl, __bf16* __restrict__ embf){
  int lane = threadIdx.x & 63, wv = threadIdx.x >> 6;
  int l15 = lane & 15, lg = lane >> 4;
  int col = blockIdx.y * 64 + wv * 16 + l15;
  const __bf16* bh_p = BTh + (size_t)col * VOC + lg * 8;
  const __bf16* bl_p = BTl + (size_t)col * VOC + lg * 8;
  size_t abase = (size_t)(blockIdx.x * 64 + l15) * VOC + lg * 8;
  const __bf16* ah_p = Ah + abase;
  const __bf16* al_p = Al + abase;
  f32x4 acc[4];
  #pragma unroll
  for (int m = 0; m < 4; m++){ acc[m][0]=0.f; acc[m][1]=0.f; acc[m][2]=0.f; acc[m][3]=0.f; }
  for (int kc = 0; kc < 16; ++kc){
    bf16x8 bh = *(const bf16x8*)(bh_p + kc * 32);
    bf16x8 bl = *(const bf16x8*)(bl_p + kc * 32);
    bf16x8 ah[4], al[4];
    #pragma unroll
    for (int m = 0; m < 4; m++){
      ah[m] = *(const bf16x8*)(ah_p + (size_t)(m * 16) * VOC + kc * 32);
      al[m] = *(const bf16x8*)(al_p + (size_t)(m * 16) * VOC + kc * 32);
    }
    #pragma unroll
    for (int m = 0; m < 4; m++) acc[m] = __builtin_amdgcn_mfma_f32_16x16x32_bf16(ah[m], bh, acc[m], 0, 0, 0);
    #pragma unroll
    for (int m = 0; m < 4; m++) acc[m] = __builtin_amdgcn_mfma_f32_16x16x32_bf16(al[m], bh, acc[m], 0, 0, 0);
    #pragma unroll
    for (int m = 0; m < 4; m++) acc[m] = __builtin_amdgcn_mfma_f32_16x16x32_bf16(ah[m], bl, acc[m], 0, 0, 0);
  }
  // hi-only frag epilogue: t = blockIdx.x, k-dim = col
  __bf16* bt = embf + (size_t)blockIdx.x * EFSZH;
  int kc = col >> 5, lgA = (col >> 3) & 3, jA = col & 7;
  #pragma unroll
  for (int m = 0; m < 4; m++){
    #pragma unroll
    for (int v = 0; v < 4; v++){
      int l15A = lg * 4 + v;
      size_t oi = (size_t)(kc * 4 + m) * 512 + (size_t)(lgA * 16 + l15A) * 8 + jA;
      bt[oi] = (__bf16)acc[m][v];
    }
  }
}

// ---- output GEMM (3-pass, exact): rn hi/lo frag history @ out_w + bias -> logits f32
__global__ __launch_bounds__(256) void gemm_out(const __bf16* __restrict__ rnf,
    const __bf16* __restrict__ BTh, const __bf16* __restrict__ BTl,
    const float* __restrict__ bias, float* __restrict__ out){
  int lane = threadIdx.x & 63, wv = threadIdx.x >> 6;
  int l15 = lane & 15, lg = lane >> 4;
  int t = blockIdx.x;
  const __bf16* ab = rnf + (size_t)(t + 1) * FRSZ;
  int col = blockIdx.y * 64 + wv * 16 + l15;
  const __bf16* bh_p = BTh + (size_t)col * NNH + lg * 8;
  const __bf16* bl_p = BTl + (size_t)col * NNH + lg * 8;
  int lane8 = lane * 8;
  f32x4 acc[4];
  #pragma unroll
  for (int m = 0; m < 4; m++){ acc[m][0]=0.f; acc[m][1]=0.f; acc[m][2]=0.f; acc[m][3]=0.f; }
  for (int kc = 0; kc < 48; ++kc){
    bf16x8 bh = *(const bf16x8*)(bh_p + kc * 32);
    bf16x8 bl = *(const bf16x8*)(bl_p + kc * 32);
    bf16x8 ah[4], al[4];
    #pragma unroll
    for (int m = 0; m < 4; m++){
      const __bf16* ap = ab + (size_t)(kc * 4 + m) * 1024 + lane8;
      ah[m] = *(const bf16x8*)ap;
      al[m] = *(const bf16x8*)(ap + 512);
    }
    #pragma unroll
    for (int m = 0; m < 4; m++) acc[m] = __builtin_amdgcn_mfma_f32_16x16x32_bf16(ah[m], bh, acc[m], 0, 0, 0);
    #pragma unroll
    for (int m = 0; m < 4; m++) acc[m] = __builtin_amdgcn_mfma_f32_16x16x32_bf16(al[m], bh, acc[m], 0, 0, 0);
    #pragma unroll
    for (int m = 0; m < 4; m++) acc[m] = __builtin_amdgcn_mfma_f32_16x16x32_bf16(ah[m], bl, acc[m], 0, 0, 0);
  }
  #pragma unroll
  for (int m = 0; m < 4; m++){
    int row = t * 64 + m * 16 + lg * 4;
    #pragma unroll
    for (int v = 0; v < 4; v++)
      out[(size_t)(row + v) * VOC + col] = acc[m][v] + bias[col];
  }
}

// ==== single-pass gate-bundled K-split region: A hi, B hi ====
// per kc: 4 A-frags + 4 B-frags, 16 MFMAs. A-ring depth 3, B-ring depth 6 (period 6).
#define AKG(S, KC) { _Pragma("unroll") \
    for (int m = 0; m < 4; m++) \
      Ah##S[m] = *(const bf16x8*)(ap + (size_t)(KC) * 2048 + m * 512 + lane8); }
#define BKG(S, KC) { _Pragma("unroll") \
    for (int g = 0; g < 4; g++) \
      Bh##S[g] = *(const bf16x8*)(bp + (size_t)(KC) * 2048 + g * 512 + lane8); }
#define MM2(SA, SB) { \
    _Pragma("unroll") for (int m = 0; m < 4; m++) _Pragma("unroll") for (int g = 0; g < 4; g++) \
      acc[m * 4 + g] = __builtin_amdgcn_mfma_f32_16x16x32_bf16(Ah##SA[m], Bh##SB[g], acc[m * 4 + g], 0, 0, 0); }

// body i: consume A-set i%3 / B-set i%6, then reload them for kc i+3 / i+6
#define BODY(I, SA, SB) \
  if ((I) < nkc){ \
    MM2(SA, SB) \
    if ((I) + 3 < nkc) AKG(SA, (I) + 3) \
    if ((I) + 6 < nkc) BKG(SB, (I) + 6) \
  }

// nkc in {6,7,8,12}; prologue reads A kc 0..2 and B kc 0..5 (valid: nkc >= 6).
// Ring verified by enumeration for nkc = 6,7,8,12: each kc loaded once into set
// (kc % depth) strictly after that set's consume (WAR-safe), consumed once.
__device__ __forceinline__ void regionKG(f32x4 (&acc)[16], const __bf16* __restrict__ ap,
                                         const __bf16* __restrict__ bp, int nkc, int lane8)
{
  bf16x8 Ah0[4], Ah1[4], Ah2[4];
  bf16x8 Bh0[4], Bh1[4], Bh2[4], Bh3[4], Bh4[4], Bh5[4];
  AKG(0, 0) AKG(1, 1) AKG(2, 2)
  BKG(0, 0) BKG(1, 1) BKG(2, 2) BKG(3, 3) BKG(4, 4) BKG(5, 5)
  BODY(0, 0, 0)
  BODY(1, 1, 1)
  BODY(2, 2, 2)
  BODY(3, 0, 3)
  BODY(4, 1, 4)
  BODY(5, 2, 5)
  BODY(6, 0, 0)
  BODY(7, 1, 1)
  BODY(8, 2, 2)
  BODY(9, 0, 3)
  BODY(10, 1, 4)
  BODY(11, 2, 5)
}

// ---- fused pipelined LSTM step: blocks 0..95 = layer0 step k; 96..191 = layer1 step k-1
// 8 waves: each wave computes full 64-col tile (16 n x 4 gates) over 1/8 of K.
// Two-stage pairwise K-reduction; h0/h1 hot hi-only ping-pong;
// rnf history keeps hi/lo (NT-streamed) so the final projection stays exact.
__global__ __launch_bounds__(512, 2) void lstm_step(int k,
  const __bf16* __restrict__ w0f, const __bf16* __restrict__ w1f,
  const float* __restrict__ b0, const float* __restrict__ b1,
  const __bf16* __restrict__ embt,
  const __bf16* __restrict__ h0r, __bf16* __restrict__ h0w,
  const __bf16* __restrict__ h1r, __bf16* __restrict__ h1w,
  __bf16* __restrict__ rnh,
  float* __restrict__ c0, float* __restrict__ c1)
{
  const bool isB = blockIdx.x >= 96;
  if (!isB && k == TT) return;
  if (isB && k == 0) return;
  const int blk = isB ? (blockIdx.x - 96) : blockIdx.x;
  const int n0 = blk * 16;
  const int lane = threadIdx.x & 63, wv = threadIdx.x >> 6;
  const int l15 = lane & 15, lg = lane >> 4;
  const int lane8 = lane * 8;

  f32x4 acc[16];
  #pragma unroll
  for (int i = 0; i < 16; i++){ acc[i][0]=0.f; acc[i][1]=0.f; acc[i][2]=0.f; acc[i][3]=0.f; }

  if (isB){
    // 96 kc; wave wv: kc [wv*12, wv*12+12); waves 0-3 read h0(t), 4-7 read h1(t-2)
    const __bf16* ap = (wv < 4) ? (h0r + (size_t)(wv * 12) * 2048)
                                : (h1r + (size_t)((wv - 4) * 12) * 2048);
    const __bf16* bp = w1f + ((size_t)blk * 96 + wv * 12) * 2048;
    regionKG(acc, ap, bp, 12, lane8);
  } else {
    // 56 kc = [emb 8 | h0 48]; quotas: wv0=8(emb), wv1-6=7, wv7=6
    int gstart = (wv == 0) ? 0 : (8 + (wv - 1) * 7);
    int nkc = (wv == 0) ? 8 : ((wv == 7) ? 6 : 7);
    const __bf16* ap = (wv == 0) ? embt : (h0r + (size_t)(gstart - 8) * 2048);
    const __bf16* bp = w0f + ((size_t)blk * 56 + gstart) * 2048;
    regionKG(acc, ap, bp, nkc, lane8);
  }

  // two-stage K-partial reduction: 8 partials -> 4 in LDS -> epilogue sums 4
  __shared__ float lin[4][64][68];   // [wavepair][col(g*16+l15)][row(batch), pad 68], ~68 KB
  if (wv >= 4){
    #pragma unroll
    for (int m = 0; m < 4; m++)
      #pragma unroll
      for (int g = 0; g < 4; g++)
        *(f32x4*)&lin[wv - 4][g * 16 + l15][m * 16 + lg * 4] = acc[m * 4 + g];
  }
  __syncthreads();
  if (wv < 4){
    #pragma unroll
    for (int m = 0; m < 4; m++)
      #pragma unroll
      for (int g = 0; g < 4; g++){
        f32x4 part = *(const f32x4*)&lin[wv][g * 16 + l15][m * 16 + lg * 4];
        acc[m * 4 + g][0] += part[0]; acc[m * 4 + g][1] += part[1];
        acc[m * 4 + g][2] += part[2]; acc[m * 4 + g][3] += part[3];
        *(f32x4*)&lin[wv][g * 16 + l15][m * 16 + lg * 4] = acc[m * 4 + g];
      }
  }
  __syncthreads();

  const float* bias = isB ? b1 : b0;
  float* cst = isB ? c1 : c0;
  __bf16* of = isB ? h1w : h0w;
  const int j = threadIdx.x & 15, rr = threadIdx.x >> 4;   // j: n_rel, rr: 0..31
  #pragma unroll
  for (int half = 0; half < 2; half++){
    int r = rr + half * 32;   // batch row
    float s0 = 0.f, s1 = 0.f, s2 = 0.f, s3 = 0.f;
    #pragma unroll
    for (int w = 0; w < 4; w++){
      s0 += lin[w][j][r];
      s1 += lin[w][16 + j][r];
      s2 += lin[w][32 + j][r];
      s3 += lin[w][48 + j][r];
    }
    int n = n0 + j;
    float fv = sigm_(s0 + bias[n]);
    float iv = sigm_(s1 + bias[NNH + n]);
    float ov = sigm_(s2 + bias[2 * NNH + n]);
    float gv = tanh_(s3 + bias[3 * NNH + n]);
    int ci = r * NNH + n;
    float cn = fv * cst[ci] + iv * gv;
    cst[ci] = cn;
    float hn = ov * tanh_(cn);
    __bf16 hb = (__bf16)hn;
    int kcp = n >> 5, lgA = (n >> 3) & 3, j8 = n & 7, mb = r >> 4, l15b = r & 15;
    // hot hi-only recurrent state
    size_t oh = (size_t)(kcp * 4 + mb) * 512 + (size_t)(lgA * 16 + l15b) * 8 + j8;
    of[oh] = hb;
    if (isB){
      // cold hi/lo history copy for exact gemm_out: stream to HBM
      __bf16 lb = (__bf16)(hn - (float)hb);
      size_t oi = (size_t)(kcp * 4 + mb) * 1024 + (size_t)(lgA * 16 + l15b) * 8 + j8;
      __builtin_nontemporal_store(hb, &rnh[oi]);
      __builtin_nontemporal_store(lb, &rnh[oi + 512]);
    }
  }
}

extern "C" void kernel_launch(void* const* d_in, const int* in_sizes, int n_in,
                              void* d_out, int out_size, void* d_ws, size_t ws_size,
                              hipStream_t stream)
{
  (void)in_sizes; (void)n_in; (void)out_size;
  const float* x_in = (const float*)d_in[0];
  const float* emw  = (const float*)d_in[1];
  const float* w0   = (const float*)d_in[2];
  const float* b0   = (const float*)d_in[3];
  const float* w1   = (const float*)d_in[4];
  const float* b1   = (const float*)d_in[5];
  const float* outw = (const float*)d_in[6];
  const float* outb = (const float*)d_in[7];
  const float* h0i  = (const float*)d_in[8];
  const float* c0i  = (const float*)d_in[9];
  const float* h1i  = (const float*)d_in[10];
  const float* c1i  = (const float*)d_in[11];
  float* logits = (float*)d_out;

  char* p = (char*)d_ws;
  auto ab = [&](size_t bytes)->char*{ char* r = p; p += (bytes + 255) & ~(size_t)255; return r; };
  __bf16* w0f  = (__bf16*)ab((size_t)96 * 56 * 4 * 1024);   // 22.0 MB hi-only stream
  __bf16* w1f  = (__bf16*)ab((size_t)96 * 96 * 4 * 1024);   // 37.7 MB
  __bf16* ewTh = (__bf16*)ab((size_t)EMBD * VOC * 2);
  __bf16* ewTl = (__bf16*)ab((size_t)EMBD * VOC * 2);
  __bf16* owTh = (__bf16*)ab((size_t)VOC * NNH * 2);
  __bf16* owTl = (__bf16*)ab((size_t)VOC * NNH * 2);
  __bf16* xh   = (__bf16*)ab((size_t)TT * BB * VOC * 2);
  __bf16* xl   = (__bf16*)ab((size_t)TT * BB * VOC * 2);
  __bf16* embf = (__bf16*)ab((size_t)TT * EFSZH * 2);       // 8.4 MB hi-only frag
  __bf16* rnf  = (__bf16*)ab((size_t)(TT + 1) * FRSZ * 2);  // 101 MB hi/lo history (NT)
  __bf16* h0f  = (__bf16*)ab((size_t)2 * FRSZH * 2);        // h0 hi-only ping-pong (hot)
  __bf16* h1f  = (__bf16*)ab((size_t)2 * FRSZH * 2);        // h1 hi-only ping-pong (hot)
  float* c0 = (float*)ab((size_t)BB * NNH * 4);
  float* c1 = (float*)ab((size_t)BB * NNH * 4);
  if ((size_t)(p - (char*)d_ws) > ws_size) return;  // ws too small: fail visibly

  const int H = BB * NNH;

  // one-time-per-call prep
  wfrag<<<96 * 56 * 4 / 4, 256, 0, stream>>>(w0, 56, w0f);
  wfrag<<<96 * 96 * 4 / 4, 256, 0, stream>>>(w1, 96, w1f);
  tsplit<<<dim3(EMBD / 32, VOC / 32), 256, 0, stream>>>(emw, VOC, EMBD, ewTh, ewTl);
  tsplit<<<dim3(VOC / 32, NNH / 32), 256, 0, stream>>>(outw, NNH, VOC, owTh, owTl);
  {
    int nin = TT * BB * VOC;
    vsplit<<<nin / 256, 256, 0, stream>>>(x_in, nin, xh, xl);
  }
  vsplit_fragH<<<H / 256, 256, 0, stream>>>(h0i, h0f + FRSZH);  // h0 parity 1 (read at k=0)
  vsplit_fragH<<<H / 256, 256, 0, stream>>>(h1i, h1f);          // h1 parity 0 (read at k=1)
  hipMemcpyAsync(c0, c0i, (size_t)H * 4, hipMemcpyDeviceToDevice, stream);
  hipMemcpyAsync(c1, c1i, (size_t)H * 4, hipMemcpyDeviceToDevice, stream);

  // embedding -> hi-only frag emb buffer
  gemm_emb<<<dim3(TT * BB / 64, EMBD / 64), 256, 0, stream>>>(xh, xl, ewTh, ewTl, embf);

  // pipelined recurrence: kernel k = layer0 step k + layer1 step k-1
  for (int k = 0; k <= TT; ++k){
    int tA = (k < TT) ? k : 0;
    lstm_step<<<192, 512, 0, stream>>>(k, w0f, w1f, b0, b1,
        embf + (size_t)tA * EFSZH,
        h0f + (size_t)((k + 1) & 1) * FRSZH, h0f + (size_t)(k & 1) * FRSZH,
        h1f + (size_t)((k + 1) & 1) * FRSZH, h1f + (size_t)(k & 1) * FRSZH,
        rnf + (size_t)k * FRSZ,
        c0, c1);
  }

  // logits = rn hi/lo frag history @ out_w + out_b (exact 3-pass)
  gemm_out<<<dim3(TT, VOC / 64), 256, 0, stream>>>(rnf, owTh, owTl, outb, logits);
}

// Round 18
// 4382.419 us; speedup vs baseline: 7.6206x; 1.0153x over previous
//
#include <hip/hip_runtime.h>
#include <hip/hip_bf16.h>

typedef __bf16 bf16x8 __attribute__((ext_vector_type(8)));
typedef float f32x4 __attribute__((ext_vector_type(4)));

#define TT 256
#define BB 64
#define VOC 512
#define EMBD 256
#define NNH 1536
#define KA 1792   // EMBD + NNH
#define KB 3072   // NNH + NNH
#define G4I 6144  // 4*NNH

// hi/lo frag buffer (rnf history): 48 kc x 4 m x (hi 512 | lo 512)
#define FRSZ 196608
// hi-only frag state (h0/h1/emb): 48 kc x 4 m x 512
#define FRSZH 98304
// emb hi-only frag per t: 8 kc x 4 m x 512
#define EFSZH 16384

__device__ __forceinline__ float sigm_(float x){
  x = fminf(fmaxf(x, -30.f), 30.f);
  return 1.f / (1.f + __expf(-x));
}
__device__ __forceinline__ float tanh_(float x){
  x = fminf(fmaxf(x, -15.f), 15.f);
  float e = __expf(2.f * x);
  return (e - 1.f) / (e + 1.f);
}

// ---- transpose + hi/lo split: src (R,C) f32 -> dst (C,R) bf16 hi/lo (for ewT/owT)
__global__ __launch_bounds__(256) void tsplit(const float* __restrict__ src, int R, int C,
                                              __bf16* __restrict__ dhi, __bf16* __restrict__ dlo){
  __shared__ float tile[32][33];
  int c0 = blockIdx.x * 32, r0 = blockIdx.y * 32;
  int tx = threadIdx.x & 31, ty = threadIdx.x >> 5;
  #pragma unroll
  for (int i = 0; i < 4; i++){
    int r = ty + i * 8;
    tile[r][tx] = src[(size_t)(r0 + r) * C + (c0 + tx)];
  }
  __syncthreads();
  #pragma unroll
  for (int i = 0; i < 4; i++){
    int cl = ty + i * 8;
    float v = tile[tx][cl];
    __bf16 h = (__bf16)v;
    size_t o = (size_t)(c0 + cl) * R + (r0 + tx);
    dhi[o] = h;
    dlo[o] = (__bf16)(v - (float)h);
  }
}

// ---- elementwise hi/lo split (x input)
__global__ __launch_bounds__(256) void vsplit(const float* __restrict__ src, int n,
                                              __bf16* __restrict__ dhi, __bf16* __restrict__ dlo){
  int i = blockIdx.x * 256 + threadIdx.x;
  if (i < n){
    float v = src[i];
    __bf16 h = (__bf16)v;
    dhi[i] = h;
    dlo[i] = (__bf16)(v - (float)h);
  }
}

// ---- h-state (64,1536) f32 -> HI-ONLY frag order
__global__ __launch_bounds__(256) void vsplit_fragH(const float* __restrict__ src,
                                                    __bf16* __restrict__ dst){
  int i = blockIdx.x * 256 + threadIdx.x;   // 0..98303
  int b = i / NNH, n = i % NNH;
  int kc = n >> 5, lgA = (n >> 3) & 3, j = n & 7;
  size_t idx = (size_t)(kc * 4 + (b >> 4)) * 512 + (size_t)(lgA * 16 + (b & 15)) * 8 + j;
  dst[idx] = (__bf16)src[i];
}

// ---- weights (K,6144) f32 -> HI-ONLY frag stream [b(96)][kc(nkc)][g(4)][512 bf16]
__global__ __launch_bounds__(256) void wfrag(const float* __restrict__ w, int nkc,
                                             __bf16* __restrict__ dst){
  int cid = blockIdx.x * 4 + (threadIdx.x >> 6);
  int lane = threadIdx.x & 63;
  int g = cid & 3;
  int bk = cid >> 2;
  int kc = bk % nkc;
  int b = bk / nkc;
  int l15 = lane & 15, lg = lane >> 4;
  int col = g * NNH + b * 16 + l15;
  int k0 = kc * 32 + lg * 8;
  bf16x8 hv;
  #pragma unroll
  for (int j = 0; j < 8; j++)
    hv[j] = (__bf16)w[(size_t)(k0 + j) * G4I + col];
  *(bf16x8*)(dst + (size_t)cid * 512 + lane * 8) = hv;
}

// ---- embedding GEMM (3-pass, exact inputs): x @ emb_w -> emb HI-ONLY frag per t
__global__ __launch_bounds__(256) void gemm_emb(const __bf16* __restrict__ Ah, const __bf16* __restrict__ Al,
    const __bf16* __restrict__ BTh, const __bf16* __restrict__ BTl, __bf16* __restrict__ embf){
  int lane = threadIdx.x & 63, wv = threadIdx.x >> 6;
  int l15 = lane & 15, lg = lane >> 4;
  int col = blockIdx.y * 64 + wv * 16 + l15;
  const __bf16* bh_p = BTh + (size_t)col * VOC + lg * 8;
  const __bf16* bl_p = BTl + (size_t)col * VOC + lg * 8;
  size_t abase = (size_t)(blockIdx.x * 64 + l15) * VOC + lg * 8;
  const __bf16* ah_p = Ah + abase;
  const __bf16* al_p = Al + abase;
  f32x4 acc[4];
  #pragma unroll
  for (int m = 0; m < 4; m++){ acc[m][0]=0.f; acc[m][1]=0.f; acc[m][2]=0.f; acc[m][3]=0.f; }
  for (int kc = 0; kc < 16; ++kc){
    bf16x8 bh = *(const bf16x8*)(bh_p + kc * 32);
    bf16x8 bl = *(const bf16x8*)(bl_p + kc * 32);
    bf16x8 ah[4], al[4];
    #pragma unroll
    for (int m = 0; m < 4; m++){
      ah[m] = *(const bf16x8*)(ah_p + (size_t)(m * 16) * VOC + kc * 32);
      al[m] = *(const bf16x8*)(al_p + (size_t)(m * 16) * VOC + kc * 32);
    }
    #pragma unroll
    for (int m = 0; m < 4; m++) acc[m] = __builtin_amdgcn_mfma_f32_16x16x32_bf16(ah[m], bh, acc[m], 0, 0, 0);
    #pragma unroll
    for (int m = 0; m < 4; m++) acc[m] = __builtin_amdgcn_mfma_f32_16x16x32_bf16(al[m], bh, acc[m], 0, 0, 0);
    #pragma unroll
    for (int m = 0; m < 4; m++) acc[m] = __builtin_amdgcn_mfma_f32_16x16x32_bf16(ah[m], bl, acc[m], 0, 0, 0);
  }
  // hi-only frag epilogue: t = blockIdx.x, k-dim = col
  __bf16* bt = embf + (size_t)blockIdx.x * EFSZH;
  int kc = col >> 5, lgA = (col >> 3) & 3, jA = col & 7;
  #pragma unroll
  for (int m = 0; m < 4; m++){
    #pragma unroll
    for (int v = 0; v < 4; v++){
      int l15A = lg * 4 + v;
      size_t oi = (size_t)(kc * 4 + m) * 512 + (size_t)(lgA * 16 + l15A) * 8 + jA;
      bt[oi] = (__bf16)acc[m][v];
    }
  }
}

// ---- output GEMM (3-pass, exact): rn hi/lo frag history @ out_w + bias -> logits f32
__global__ __launch_bounds__(256) void gemm_out(const __bf16* __restrict__ rnf,
    const __bf16* __restrict__ BTh, const __bf16* __restrict__ BTl,
    const float* __restrict__ bias, float* __restrict__ out){
  int lane = threadIdx.x & 63, wv = threadIdx.x >> 6;
  int l15 = lane & 15, lg = lane >> 4;
  int t = blockIdx.x;
  const __bf16* ab = rnf + (size_t)(t + 1) * FRSZ;
  int col = blockIdx.y * 64 + wv * 16 + l15;
  const __bf16* bh_p = BTh + (size_t)col * NNH + lg * 8;
  const __bf16* bl_p = BTl + (size_t)col * NNH + lg * 8;
  int lane8 = lane * 8;
  f32x4 acc[4];
  #pragma unroll
  for (int m = 0; m < 4; m++){ acc[m][0]=0.f; acc[m][1]=0.f; acc[m][2]=0.f; acc[m][3]=0.f; }
  for (int kc = 0; kc < 48; ++kc){
    bf16x8 bh = *(const bf16x8*)(bh_p + kc * 32);
    bf16x8 bl = *(const bf16x8*)(bl_p + kc * 32);
    bf16x8 ah[4], al[4];
    #pragma unroll
    for (int m = 0; m < 4; m++){
      const __bf16* ap = ab + (size_t)(kc * 4 + m) * 1024 + lane8;
      ah[m] = *(const bf16x8*)ap;
      al[m] = *(const bf16x8*)(ap + 512);
    }
    #pragma unroll
    for (int m = 0; m < 4; m++) acc[m] = __builtin_amdgcn_mfma_f32_16x16x32_bf16(ah[m], bh, acc[m], 0, 0, 0);
    #pragma unroll
    for (int m = 0; m < 4; m++) acc[m] = __builtin_amdgcn_mfma_f32_16x16x32_bf16(al[m], bh, acc[m], 0, 0, 0);
    #pragma unroll
    for (int m = 0; m < 4; m++) acc[m] = __builtin_amdgcn_mfma_f32_16x16x32_bf16(ah[m], bl, acc[m], 0, 0, 0);
  }
  #pragma unroll
  for (int m = 0; m < 4; m++){
    int row = t * 64 + m * 16 + lg * 4;
    #pragma unroll
    for (int v = 0; v < 4; v++)
      out[(size_t)(row + v) * VOC + col] = acc[m][v] + bias[col];
  }
}

// ==== single-pass gate-bundled K-split region: A hi, B hi ====
// per kc: 4 A-frags + 4 B-frags, 16 MFMAs. A-ring depth 3, B-ring depth 4 (period 12).
#define AKG(S, KC) { _Pragma("unroll") \
    for (int m = 0; m < 4; m++) \
      Ah##S[m] = *(const bf16x8*)(ap + (size_t)(KC) * 2048 + m * 512 + lane8); }
#define BKG(S, KC) { _Pragma("unroll") \
    for (int g = 0; g < 4; g++) \
      Bh##S[g] = *(const bf16x8*)(bp + (size_t)(KC) * 2048 + g * 512 + lane8); }
#define MM2(SA, SB) { \
    _Pragma("unroll") for (int m = 0; m < 4; m++) _Pragma("unroll") for (int g = 0; g < 4; g++) \
      acc[m * 4 + g] = __builtin_amdgcn_mfma_f32_16x16x32_bf16(Ah##SA[m], Bh##SB[g], acc[m * 4 + g], 0, 0, 0); }

// body i: consume A-set i%3 / B-set i%4, then reload them for kc i+3 / i+4
#define BODY(I, SA, SB) \
  if ((I) < nkc){ \
    MM2(SA, SB) \
    if ((I) + 3 < nkc) AKG(SA, (I) + 3) \
    if ((I) + 4 < nkc) BKG(SB, (I) + 4) \
  }

// nkc in {6,7,8,12}; fully unrolled 12 slots, wave-uniform guards
__device__ __forceinline__ void regionKG(f32x4 (&acc)[16], const __bf16* __restrict__ ap,
                                         const __bf16* __restrict__ bp, int nkc, int lane8)
{
  bf16x8 Ah0[4], Ah1[4], Ah2[4];
  bf16x8 Bh0[4], Bh1[4], Bh2[4], Bh3[4];
  AKG(0, 0) AKG(1, 1) AKG(2, 2)
  BKG(0, 0) BKG(1, 1) BKG(2, 2) BKG(3, 3)
  BODY(0, 0, 0)
  BODY(1, 1, 1)
  BODY(2, 2, 2)
  BODY(3, 0, 3)
  BODY(4, 1, 0)
  BODY(5, 2, 1)
  BODY(6, 0, 2)
  BODY(7, 1, 3)
  BODY(8, 2, 0)
  BODY(9, 0, 1)
  BODY(10, 1, 2)
  BODY(11, 2, 3)
}

// ---- fused pipelined LSTM step: blocks 0..95 = layer0 step k; 96..191 = layer1 step k-1
// 8 waves: each wave computes full 64-col tile (16 n x 4 gates) over 1/8 of K.
// Two-stage pairwise K-reduction; h0/h1 hot hi-only ping-pong;
// rnf history keeps hi/lo (NT-streamed) so the final projection stays exact.
__global__ __launch_bounds__(512, 2) void lstm_step(int k,
  const __bf16* __restrict__ w0f, const __bf16* __restrict__ w1f,
  const float* __restrict__ b0, const float* __restrict__ b1,
  const __bf16* __restrict__ embt,
  const __bf16* __restrict__ h0r, __bf16* __restrict__ h0w,
  const __bf16* __restrict__ h1r, __bf16* __restrict__ h1w,
  __bf16* __restrict__ rnh,
  float* __restrict__ c0, float* __restrict__ c1)
{
  const bool isB = blockIdx.x >= 96;
  if (!isB && k == TT) return;
  if (isB && k == 0) return;
  const int blk = isB ? (blockIdx.x - 96) : blockIdx.x;
  const int n0 = blk * 16;
  const int lane = threadIdx.x & 63, wv = threadIdx.x >> 6;
  const int l15 = lane & 15, lg = lane >> 4;
  const int lane8 = lane * 8;

  f32x4 acc[16];
  #pragma unroll
  for (int i = 0; i < 16; i++){ acc[i][0]=0.f; acc[i][1]=0.f; acc[i][2]=0.f; acc[i][3]=0.f; }

  if (isB){
    // 96 kc; wave wv: kc [wv*12, wv*12+12); waves 0-3 read h0(t), 4-7 read h1(t-2)
    const __bf16* ap = (wv < 4) ? (h0r + (size_t)(wv * 12) * 2048)
                                : (h1r + (size_t)((wv - 4) * 12) * 2048);
    const __bf16* bp = w1f + ((size_t)blk * 96 + wv * 12) * 2048;
    regionKG(acc, ap, bp, 12, lane8);
  } else {
    // 56 kc = [emb 8 | h0 48]; quotas: wv0=8(emb), wv1-6=7, wv7=6
    int gstart = (wv == 0) ? 0 : (8 + (wv - 1) * 7);
    int nkc = (wv == 0) ? 8 : ((wv == 7) ? 6 : 7);
    const __bf16* ap = (wv == 0) ? embt : (h0r + (size_t)(gstart - 8) * 2048);
    const __bf16* bp = w0f + ((size_t)blk * 56 + gstart) * 2048;
    regionKG(acc, ap, bp, nkc, lane8);
  }

  // two-stage K-partial reduction: 8 partials -> 4 in LDS -> epilogue sums 4
  __shared__ float lin[4][64][68];   // [wavepair][col(g*16+l15)][row(batch), pad 68], ~68 KB
  if (wv >= 4){
    #pragma unroll
    for (int m = 0; m < 4; m++)
      #pragma unroll
      for (int g = 0; g < 4; g++)
        *(f32x4*)&lin[wv - 4][g * 16 + l15][m * 16 + lg * 4] = acc[m * 4 + g];
  }
  __syncthreads();
  if (wv < 4){
    #pragma unroll
    for (int m = 0; m < 4; m++)
      #pragma unroll
      for (int g = 0; g < 4; g++){
        f32x4 part = *(const f32x4*)&lin[wv][g * 16 + l15][m * 16 + lg * 4];
        acc[m * 4 + g][0] += part[0]; acc[m * 4 + g][1] += part[1];
        acc[m * 4 + g][2] += part[2]; acc[m * 4 + g][3] += part[3];
        *(f32x4*)&lin[wv][g * 16 + l15][m * 16 + lg * 4] = acc[m * 4 + g];
      }
  }
  __syncthreads();

  const float* bias = isB ? b1 : b0;
  float* cst = isB ? c1 : c0;
  __bf16* of = isB ? h1w : h0w;
  const int j = threadIdx.x & 15, rr = threadIdx.x >> 4;   // j: n_rel, rr: 0..31
  #pragma unroll
  for (int half = 0; half < 2; half++){
    int r = rr + half * 32;   // batch row
    float s0 = 0.f, s1 = 0.f, s2 = 0.f, s3 = 0.f;
    #pragma unroll
    for (int w = 0; w < 4; w++){
      s0 += lin[w][j][r];
      s1 += lin[w][16 + j][r];
      s2 += lin[w][32 + j][r];
      s3 += lin[w][48 + j][r];
    }
    int n = n0 + j;
    float fv = sigm_(s0 + bias[n]);
    float iv = sigm_(s1 + bias[NNH + n]);
    float ov = sigm_(s2 + bias[2 * NNH + n]);
    float gv = tanh_(s3 + bias[3 * NNH + n]);
    int ci = r * NNH + n;
    float cn = fv * cst[ci] + iv * gv;
    cst[ci] = cn;
    float hn = ov * tanh_(cn);
    __bf16 hb = (__bf16)hn;
    int kcp = n >> 5, lgA = (n >> 3) & 3, j8 = n & 7, mb = r >> 4, l15b = r & 15;
    // hot hi-only recurrent state
    size_t oh = (size_t)(kcp * 4 + mb) * 512 + (size_t)(lgA * 16 + l15b) * 8 + j8;
    of[oh] = hb;
    if (isB){
      // cold hi/lo history copy for exact gemm_out: stream to HBM
      __bf16 lb = (__bf16)(hn - (float)hb);
      size_t oi = (size_t)(kcp * 4 + mb) * 1024 + (size_t)(lgA * 16 + l15b) * 8 + j8;
      __builtin_nontemporal_store(hb, &rnh[oi]);
      __builtin_nontemporal_store(lb, &rnh[oi + 512]);
    }
  }
}

extern "C" void kernel_launch(void* const* d_in, const int* in_sizes, int n_in,
                              void* d_out, int out_size, void* d_ws, size_t ws_size,
                              hipStream_t stream)
{
  (void)in_sizes; (void)n_in; (void)out_size;
  const float* x_in = (const float*)d_in[0];
  const float* emw  = (const float*)d_in[1];
  const float* w0   = (const float*)d_in[2];
  const float* b0   = (const float*)d_in[3];
  const float* w1   = (const float*)d_in[4];
  const float* b1   = (const float*)d_in[5];
  const float* outw = (const float*)d_in[6];
  const float* outb = (const float*)d_in[7];
  const float* h0i  = (const float*)d_in[8];
  const float* c0i  = (const float*)d_in[9];
  const float* h1i  = (const float*)d_in[10];
  const float* c1i  = (const float*)d_in[11];
  float* logits = (float*)d_out;

  char* p = (char*)d_ws;
  auto ab = [&](size_t bytes)->char*{ char* r = p; p += (bytes + 255) & ~(size_t)255; return r; };
  __bf16* w0f  = (__bf16*)ab((size_t)96 * 56 * 4 * 1024);   // 22.0 MB hi-only stream
  __bf16* w1f  = (__bf16*)ab((size_t)96 * 96 * 4 * 1024);   // 37.7 MB
  __bf16* ewTh = (__bf16*)ab((size_t)EMBD * VOC * 2);
  __bf16* ewTl = (__bf16*)ab((size_t)EMBD * VOC * 2);
  __bf16* owTh = (__bf16*)ab((size_t)VOC * NNH * 2);
  __bf16* owTl = (__bf16*)ab((size_t)VOC * NNH * 2);
  __bf16* xh   = (__bf16*)ab((size_t)TT * BB * VOC * 2);
  __bf16* xl   = (__bf16*)ab((size_t)TT * BB * VOC * 2);
  __bf16* embf = (__bf16*)ab((size_t)TT * EFSZH * 2);       // 8.4 MB hi-only frag
  __bf16* rnf  = (__bf16*)ab((size_t)(TT + 1) * FRSZ * 2);  // 101 MB hi/lo history (NT)
  __bf16* h0f  = (__bf16*)ab((size_t)2 * FRSZH * 2);        // h0 hi-only ping-pong (hot)
  __bf16* h1f  = (__bf16*)ab((size_t)2 * FRSZH * 2);        // h1 hi-only ping-pong (hot)
  float* c0 = (float*)ab((size_t)BB * NNH * 4);
  float* c1 = (float*)ab((size_t)BB * NNH * 4);
  if ((size_t)(p - (char*)d_ws) > ws_size) return;  // ws too small: fail visibly

  const int H = BB * NNH;

  // one-time-per-call prep
  wfrag<<<96 * 56 * 4 / 4, 256, 0, stream>>>(w0, 56, w0f);
  wfrag<<<96 * 96 * 4 / 4, 256, 0, stream>>>(w1, 96, w1f);
  tsplit<<<dim3(EMBD / 32, VOC / 32), 256, 0, stream>>>(emw, VOC, EMBD, ewTh, ewTl);
  tsplit<<<dim3(VOC / 32, NNH / 32), 256, 0, stream>>>(outw, NNH, VOC, owTh, owTl);
  {
    int nin = TT * BB * VOC;
    vsplit<<<nin / 256, 256, 0, stream>>>(x_in, nin, xh, xl);
  }
  vsplit_fragH<<<H / 256, 256, 0, stream>>>(h0i, h0f + FRSZH);  // h0 parity 1 (read at k=0)
  vsplit_fragH<<<H / 256, 256, 0, stream>>>(h1i, h1f);          // h1 parity 0 (read at k=1)
  hipMemcpyAsync(c0, c0i, (size_t)H * 4, hipMemcpyDeviceToDevice, stream);
  hipMemcpyAsync(c1, c1i, (size_t)H * 4, hipMemcpyDeviceToDevice, stream);

  // embedding -> hi-only frag emb buffer
  gemm_emb<<<dim3(TT * BB / 64, EMBD / 64), 256, 0, stream>>>(xh, xl, ewTh, ewTl, embf);

  // pipelined recurrence: kernel k = layer0 step k + layer1 step k-1
  for (int k = 0; k <= TT; ++k){
    int tA = (k < TT) ? k : 0;
    lstm_step<<<192, 512, 0, stream>>>(k, w0f, w1f, b0, b1,
        embf + (size_t)tA * EFSZH,
        h0f + (size_t)((k + 1) & 1) * FRSZH, h0f + (size_t)(k & 1) * FRSZH,
        h1f + (size_t)((k + 1) & 1) * FRSZH, h1f + (size_t)(k & 1) * FRSZH,
        rnf + (size_t)k * FRSZ,
        c0, c1);
  }

  // logits = rn hi/lo frag history @ out_w + out_b (exact 3-pass)
  gemm_out<<<dim3(TT, VOC / 64), 256, 0, stream>>>(rnf, owTh, owTl, outb, logits);
}